// Round 1
// baseline (104.376 us; speedup 1.0000x reference)
//
#include <hip/hip_runtime.h>
#include <stdint.h>

#define IN_F   4096   // output width / weight cols
#define OUT_F  4096   // x width / weight rows
#define BATCH  8192

__device__ __forceinline__ uint32_t fkey(float v) {
    // monotone float -> uint mapping (order-preserving for all finite values)
    uint32_t u = __float_as_uint(v);
    return (u & 0x80000000u) ? ~u : (u | 0x80000000u);
}

// A1: partial column-argmax over a row chunk.
// grid (IN_F/1024, chunks), block 256. Each thread owns 4 adjacent columns (float4 loads).
__global__ __launch_bounds__(256) void argmax_partial(
        const float* __restrict__ w,
        unsigned long long* __restrict__ part,
        int rowsPerChunk) {
    int c4 = blockIdx.x * 256 + threadIdx.x;      // float4-column index [0, 1024)
    int r0 = blockIdx.y * rowsPerChunk;
    int r1 = r0 + rowsPerChunk; if (r1 > OUT_F) r1 = OUT_F;
    const float4* w4 = (const float4*)w;
    float best0 = -INFINITY, best1 = -INFINITY, best2 = -INFINITY, best3 = -INFINITY;
    int i0 = 0, i1 = 0, i2 = 0, i3 = 0;
    for (int r = r0; r < r1; ++r) {
        float4 v = w4[(size_t)r * (IN_F / 4) + c4];
        if (v.x > best0) { best0 = v.x; i0 = r; }   // '>' keeps FIRST occurrence
        if (v.y > best1) { best1 = v.y; i1 = r; }
        if (v.z > best2) { best2 = v.z; i2 = r; }
        if (v.w > best3) { best3 = v.w; i3 = r; }
    }
    size_t base = (size_t)blockIdx.y * IN_F + (size_t)c4 * 4;
    // pack: key in high 32, ~idx in low 32 -> u64 max == (max val, then min idx)
    part[base + 0] = ((unsigned long long)fkey(best0) << 32) | (uint32_t)(~i0);
    part[base + 1] = ((unsigned long long)fkey(best1) << 32) | (uint32_t)(~i1);
    part[base + 2] = ((unsigned long long)fkey(best2) << 32) | (uint32_t)(~i2);
    part[base + 3] = ((unsigned long long)fkey(best3) << 32) | (uint32_t)(~i3);
}

// A2: reduce chunk partials -> ii[c]
__global__ __launch_bounds__(256) void argmax_final(
        const unsigned long long* __restrict__ part,
        int* __restrict__ ii, int chunks) {
    int c = blockIdx.x * 256 + threadIdx.x;
    if (c >= IN_F) return;
    unsigned long long best = 0ull;
    for (int k = 0; k < chunks; ++k) {
        unsigned long long p = part[(size_t)k * IN_F + c];
        if (p > best) best = p;
    }
    ii[c] = (int)(~(uint32_t)best);
}

// G: one block per row. Stage x-row in LDS (coalesced), gather from LDS,
// store coalesced float4. All HBM traffic stays fully coalesced.
__global__ __launch_bounds__(256) void gather_rows(
        const float* __restrict__ x,
        const int* __restrict__ ii,
        float* __restrict__ y) {
    __shared__ float xrow[OUT_F];          // 16 KiB
    int b = blockIdx.x;
    const float4* x4 = (const float4*)(x + (size_t)b * OUT_F);
    float4* s4 = (float4*)xrow;
    #pragma unroll
    for (int i = 0; i < OUT_F / 4 / 256; ++i)
        s4[i * 256 + threadIdx.x] = x4[i * 256 + threadIdx.x];
    __syncthreads();
    const int4* ii4 = (const int4*)ii;
    float4* y4 = (float4*)(y + (size_t)b * IN_F);
    #pragma unroll
    for (int p = 0; p < IN_F / 4 / 256; ++p) {
        int j4 = p * 256 + threadIdx.x;
        int4 id = ii4[j4];
        float4 o;
        o.x = xrow[id.x]; o.y = xrow[id.y]; o.z = xrow[id.z]; o.w = xrow[id.w];
        y4[j4] = o;
    }
}

extern "C" void kernel_launch(void* const* d_in, const int* in_sizes, int n_in,
                              void* d_out, int out_size, void* d_ws, size_t ws_size,
                              hipStream_t stream) {
    const float* x = (const float*)d_in[0];   // (BATCH, OUT_F)
    const float* w = (const float*)d_in[1];   // (OUT_F, IN_F)
    float* y = (float*)d_out;                 // (BATCH, IN_F)

    // ws layout: [ part: chunks * IN_F * 8 B ][ ii: IN_F * 4 B ]
    const size_t iiBytes = (size_t)IN_F * sizeof(int);
    long long avail = (long long)ws_size - (long long)iiBytes;
    int chunks = (int)(avail / ((long long)IN_F * 8));
    if (chunks < 1)  chunks = 1;
    if (chunks > 64) chunks = 64;
    unsigned long long* part = (unsigned long long*)d_ws;
    int* ii = (int*)((char*)d_ws + (size_t)chunks * IN_F * 8);
    int rowsPer = (OUT_F + chunks - 1) / chunks;

    dim3 g1(IN_F / (256 * 4), chunks);
    argmax_partial<<<g1, 256, 0, stream>>>(w, part, rowsPer);
    argmax_final<<<IN_F / 256, 256, 0, stream>>>(part, ii, chunks);
    gather_rows<<<BATCH, 256, 0, stream>>>(x, ii, y);
}

// Round 2
// 81.132 us; speedup vs baseline: 1.2865x; 1.2865x over previous
//
#include <hip/hip_runtime.h>
#include <stdint.h>

#define IN_F   4096   // output width / weight cols
#define OUT_F  4096   // x width / weight rows
#define BATCH  8192

__device__ __forceinline__ uint32_t fkey(float v) {
    // monotone float -> uint mapping (order-preserving for all finite values)
    uint32_t u = __float_as_uint(v);
    return (u & 0x80000000u) ? ~u : (u | 0x80000000u);
}

// A1: partial column-argmax over a row chunk.
// grid (IN_F/1024, chunks), block 256. Each thread owns 4 adjacent columns (float4 loads).
__global__ __launch_bounds__(256) void argmax_partial(
        const float* __restrict__ w,
        unsigned long long* __restrict__ part,
        int rowsPerChunk) {
    int c4 = blockIdx.x * 256 + threadIdx.x;      // float4-column index [0, 1024)
    int r0 = blockIdx.y * rowsPerChunk;
    int r1 = r0 + rowsPerChunk; if (r1 > OUT_F) r1 = OUT_F;
    const float4* w4 = (const float4*)w;
    float best0 = -INFINITY, best1 = -INFINITY, best2 = -INFINITY, best3 = -INFINITY;
    int i0 = 0, i1 = 0, i2 = 0, i3 = 0;
    #pragma unroll 8
    for (int r = r0; r < r1; ++r) {
        float4 v = w4[(size_t)r * (IN_F / 4) + c4];
        if (v.x > best0) { best0 = v.x; i0 = r; }   // '>' keeps FIRST occurrence
        if (v.y > best1) { best1 = v.y; i1 = r; }
        if (v.z > best2) { best2 = v.z; i2 = r; }
        if (v.w > best3) { best3 = v.w; i3 = r; }
    }
    size_t base = (size_t)blockIdx.y * IN_F + (size_t)c4 * 4;
    // pack: key in high 32, ~idx in low 32 -> u64 max == (max val, then min idx)
    part[base + 0] = ((unsigned long long)fkey(best0) << 32) | (uint32_t)(~i0);
    part[base + 1] = ((unsigned long long)fkey(best1) << 32) | (uint32_t)(~i1);
    part[base + 2] = ((unsigned long long)fkey(best2) << 32) | (uint32_t)(~i2);
    part[base + 3] = ((unsigned long long)fkey(best3) << 32) | (uint32_t)(~i3);
}

// A2: reduce chunk partials -> ii[c].  grid 64, block 64 (one column per thread,
// coalesced 512B/wave loads; partials are L2-resident).
__global__ __launch_bounds__(64) void argmax_final(
        const unsigned long long* __restrict__ part,
        int* __restrict__ ii, int chunks) {
    int c = blockIdx.x * 64 + threadIdx.x;
    if (c >= IN_F) return;
    unsigned long long best = 0ull;
    #pragma unroll 4
    for (int k = 0; k < chunks; ++k) {
        unsigned long long p = part[(size_t)k * IN_F + c];
        if (p > best) best = p;
    }
    ii[c] = (int)(~(uint32_t)best);
}

// G: one block per row. Stage x-row in LDS (coalesced), gather from LDS,
// store coalesced float4. All HBM traffic stays fully coalesced.
__global__ __launch_bounds__(256) void gather_rows(
        const float* __restrict__ x,
        const int* __restrict__ ii,
        float* __restrict__ y) {
    __shared__ float xrow[OUT_F];          // 16 KiB
    int b = blockIdx.x;
    const float4* x4 = (const float4*)(x + (size_t)b * OUT_F);
    float4* s4 = (float4*)xrow;
    #pragma unroll
    for (int i = 0; i < OUT_F / 4 / 256; ++i)
        s4[i * 256 + threadIdx.x] = x4[i * 256 + threadIdx.x];
    __syncthreads();
    const int4* ii4 = (const int4*)ii;
    float4* y4 = (float4*)(y + (size_t)b * IN_F);
    #pragma unroll
    for (int p = 0; p < IN_F / 4 / 256; ++p) {
        int j4 = p * 256 + threadIdx.x;
        int4 id = ii4[j4];
        float4 o;
        o.x = xrow[id.x]; o.y = xrow[id.y]; o.z = xrow[id.z]; o.w = xrow[id.w];
        y4[j4] = o;
    }
}

extern "C" void kernel_launch(void* const* d_in, const int* in_sizes, int n_in,
                              void* d_out, int out_size, void* d_ws, size_t ws_size,
                              hipStream_t stream) {
    const float* x = (const float*)d_in[0];   // (BATCH, OUT_F)
    const float* w = (const float*)d_in[1];   // (OUT_F, IN_F)
    float* y = (float*)d_out;                 // (BATCH, IN_F)

    // ws layout: [ part: chunks * IN_F * 8 B ][ ii: IN_F * 4 B ]
    const size_t iiBytes = (size_t)IN_F * sizeof(int);
    long long avail = (long long)ws_size - (long long)iiBytes;
    int chunks = (int)(avail / ((long long)IN_F * 8));
    if (chunks < 1)   chunks = 1;
    if (chunks > 128) chunks = 128;          // grid (4,128) = 512 blocks = 2/CU
    unsigned long long* part = (unsigned long long*)d_ws;
    int* ii = (int*)((char*)d_ws + (size_t)chunks * IN_F * 8);
    int rowsPer = (OUT_F + chunks - 1) / chunks;

    dim3 g1(IN_F / (256 * 4), chunks);
    argmax_partial<<<g1, 256, 0, stream>>>(w, part, rowsPer);
    argmax_final<<<IN_F / 64, 64, 0, stream>>>(part, ii, chunks);
    gather_rows<<<BATCH, 256, 0, stream>>>(x, ii, y);
}